// Round 7
// baseline (214.967 us; speedup 1.0000x reference)
//
#include <hip/hip_runtime.h>

#define SDIM 14
#define L_COORD 5.0f
#define L_NOOBJ 0.5f
#define BATCH 4096
#define CELLS (BATCH * SDIM * SDIM)   // 802816
#define BLOCK 256
#define CPB 256                       // cells per block
#define NBLOCKS (CELLS / CPB)         // 3136
#define BSTR 11                       // box row stride (pad 10 -> 11)

// R4 structure (24 KB LDS -> high occupancy, coalesced float2 stream) with the
// load cluster pinned by sched_barrier(0): all 30 loads issue back-to-back and
// stay in flight (~15 KB/wave outstanding), instead of being sunk to their uses
// (R4/R5 had VGPR=40 and ~3 loads in flight -> latency-bound at ~1 TB/s).
__global__ __launch_bounds__(BLOCK, 4) void yolo_loss(
    const float* __restrict__ pred, const float* __restrict__ targ,
    float* __restrict__ out) {
    __shared__ float bP[CPB * BSTR];   // 2816 floats
    __shared__ float bT[CPB * BSTR];
    __shared__ float cls[CPB];
    __shared__ float wsum[BLOCK / 64];

    const int tid = threadIdx.x;
    cls[tid] = 0.0f;
    __syncthreads();                   // zeroing visible before any atomicAdd

    const size_t base2 = (size_t)blockIdx.x * (CPB * 30 / 2);
    const float2* p2 = reinterpret_cast<const float2*>(pred) + base2;
    const float2* t2 = reinterpret_cast<const float2*>(targ) + base2;

    // ---- phase 1: clustered coalesced loads (pinned before any use) ----
    float2 pv[15], tv[15];
#pragma unroll
    for (int j = 0; j < 15; ++j) pv[j] = p2[tid + j * BLOCK];
#pragma unroll
    for (int j = 0; j < 15; ++j) tv[j] = t2[tid + j * BLOCK];
    __builtin_amdgcn_sched_barrier(0); // hard fence: no reordering across

    // ---- phase 2: scatter box channels to LDS / reduce class channels ----
#pragma unroll
    for (int j = 0; j < 15; ++j) {
        const int idx = tid + j * BLOCK;       // 0..3839
        const int e0 = idx * 2;                // even element offset in block span
        const int cell = e0 / 30;              // 0..255 (magic-mul)
        const int ch = e0 - cell * 30;         // even; float2 never straddles a cell
        if (ch < 10) {                         // both elements box channels
            const int o = cell * BSTR + ch;
            bP[o] = pv[j].x; bP[o + 1] = pv[j].y;
            bT[o] = tv[j].x; bT[o + 1] = tv[j].y;
        } else {                               // both elements class channels
            const float d0 = pv[j].x - tv[j].x;
            const float d1 = pv[j].y - tv[j].y;
            atomicAdd(&cls[cell], d0 * d0 + d1 * d1);
        }
    }
    __syncthreads();

    // ---- per-cell epilogue: thread tid owns local cell tid ----
    const float* P = bP + tid * BSTR;
    const float* T = bT + tid * BSTR;
    const float obj = T[4];            // exactly 0.0 or 1.0
    const float noobj = 1.0f - obj;

    const float invS = 1.0f / (float)SDIM;
    const float t1x = T[0] * invS - T[2] * 0.5f;
    const float t1y = T[1] * invS - T[3] * 0.5f;
    const float t2x = T[0] * invS + T[2] * 0.5f;
    const float t2y = T[1] * invS + T[3] * 0.5f;
    const float area_t = (t2x - t1x) * (t2y - t1y);

    float iou0 = 0.0f, iou1 = 0.0f;
#pragma unroll
    for (int k = 0; k < 2; ++k) {
        const float bx = P[5 * k + 0], by = P[5 * k + 1];
        const float bw = P[5 * k + 2], bh = P[5 * k + 3];
        const float p1x = bx * invS - bw * 0.5f;
        const float p1y = by * invS - bh * 0.5f;
        const float p2x = bx * invS + bw * 0.5f;
        const float p2y = by * invS + bh * 0.5f;
        const float ltx = fmaxf(p1x, t1x), lty = fmaxf(p1y, t1y);
        const float rbx = fminf(p2x, t2x), rby = fminf(p2y, t2y);
        const float wx = fmaxf(rbx - ltx, 0.0f);
        const float wy = fmaxf(rby - lty, 0.0f);
        const float inter = wx * wy;
        const float area_p = (p2x - p1x) * (p2y - p1y);
        const float v = inter / (area_p + area_t - inter);
        if (k == 0) iou0 = v; else iou1 = v;
    }
    const bool pick1 = (iou0 <= iou1);
    const float iou_best = pick1 ? iou1 : iou0;
    const float psx = pick1 ? P[5] : P[0];
    const float psy = pick1 ? P[6] : P[1];
    const float psw = pick1 ? P[7] : P[2];
    const float psh = pick1 ? P[8] : P[3];
    const float psc = pick1 ? P[9] : P[4];
    const float tsx = pick1 ? T[5] : T[0];
    const float tsy = pick1 ? T[6] : T[1];
    const float tsw = pick1 ? T[7] : T[2];
    const float tsh = pick1 ? T[8] : T[3];

    const float dx = psx - tsx, dy = psy - tsy;
    const float dw = sqrtf(psw) - sqrtf(tsw);
    const float dh = sqrtf(psh) - sqrtf(tsh);
    const float reg = dx * dx + dy * dy + dw * dw + dh * dh;
    const float dconf = psc - iou_best;
    const float d4 = P[4] - T[4];
    const float d9 = P[9] - T[9];

    float loss = obj * (cls[tid] + L_COORD * reg + dconf * dconf)
               + L_NOOBJ * noobj * (d4 * d4 + d9 * d9);

    // ---- wave shuffle reduction -> block sum -> one global atomic ----
#pragma unroll
    for (int off = 32; off > 0; off >>= 1)
        loss += __shfl_down(loss, off, 64);
    const int lane = tid & 63;
    const int wave = tid >> 6;
    if (lane == 0) wsum[wave] = loss;
    __syncthreads();
    if (tid == 0) {
        const float bsum = wsum[0] + wsum[1] + wsum[2] + wsum[3];
        atomicAdd(out, bsum * (1.0f / (float)BATCH));
    }
}

extern "C" void kernel_launch(void* const* d_in, const int* in_sizes, int n_in,
                              void* d_out, int out_size, void* d_ws, size_t ws_size,
                              hipStream_t stream) {
    const float* pred = (const float*)d_in[0];
    const float* targ = (const float*)d_in[1];
    float* out = (float*)d_out;

    hipMemsetAsync(out, 0, sizeof(float), stream);   // capturable memset node
    yolo_loss<<<NBLOCKS, BLOCK, 0, stream>>>(pred, targ, out);
}